// Round 5
// baseline (99.853 us; speedup 1.0000x reference)
//
#include <hip/hip_runtime.h>
#include <hip/hip_bf16.h>
#include <math.h>

#define NB   256
#define KIN  1024
#define ND   512
#define NP   2048
#define NTOT 4096   // Wm rows + proxy rows stacked

typedef __bf16 bf16x8 __attribute__((ext_vector_type(8)));
typedef float  f32x4  __attribute__((ext_vector_type(4)));
typedef unsigned short ush8 __attribute__((ext_vector_type(8)));

// ws byte offsets (16B aligned)
#define OFF_WPB    0u          // 4096*512 bf16 = 4 MB   (proxy rows pre-scaled by 2)
#define OFF_FEAT32 4194304u    // 256*512 f32   = 512 KB (feat + bias, for row norms)
#define OFF_FEATB  4718592u    // 256*512 bf16  = 256 KB (feat + bias, head A operand)
#define OFF_PN2    4980736u    // 2048 f32      = 8 KB
#define OFF_LOGITS 4988928u    // 256*2048 f32  = 2 MB
#define OFF_PMX    7086080u    // 32*256 f32    = 32 KB  (per-tile row max)
#define OFF_PSUM   7118848u    // 32*256 f32    = 32 KB  (per-tile row sumexp)
#define OFF_CNT    7151616u    // 4 ints        (proxy-tile completion counters)

__device__ __forceinline__ ush8 pack8(float4 f0, float4 f1) {
    union { ush8 v; __hip_bfloat162 h[4]; } o;
    o.h[0] = __float22bfloat162_rn(make_float2(f0.x, f0.y));
    o.h[1] = __float22bfloat162_rn(make_float2(f0.z, f0.w));
    o.h[2] = __float22bfloat162_rn(make_float2(f1.x, f1.y));
    o.h[3] = __float22bfloat162_rn(make_float2(f1.z, f1.w));
    return o.v;
}
__device__ __forceinline__ unsigned short f2bf(float v) {
    union { __hip_bfloat16 h; unsigned short u; } c;
    c.h = __float2bfloat16(v);
    return c.u;
}
// load 8 consecutive fp32, convert to bf16x8 fragment (register-only)
__device__ __forceinline__ bf16x8 ldf8(const float* p) {
    float4 v0 = *(const float4*)p, v1 = *(const float4*)(p + 4);
    union { ush8 u; bf16x8 b; } c;
    c.u = pack8(v0, v1);
    return c.b;
}

// ---------------------------------------------------------------------------
// K1: fused prep + feat. 384 blocks.  (round-4 proven; + counter zeroing)
//  blocks 0..127  : feat GEMM, one 32x32 tile per block, split-K=4 across the
//                   4 waves (8 reg-direct K-steps each), 4-way LDS reduce,
//                   write feat32 (f32+bias) + featb (bf16).
//  blocks 128..383: cast Wm (x1) / prox (x2) -> WPb, pn2 = ||prox||^2,
//                   block 128 zeroes tail accumulators + proxy counters.
// ---------------------------------------------------------------------------
__global__ __launch_bounds__(256) void k1_featprep(
    const float* __restrict__ x, const float* __restrict__ Wb,
    const float* __restrict__ bb,
    const float* __restrict__ Wm, const float* __restrict__ prox,
    unsigned short* __restrict__ WPb, float* __restrict__ pn2,
    float* __restrict__ feat32, unsigned short* __restrict__ featb,
    float* __restrict__ tail, int* __restrict__ cnt)
{
    __shared__ __align__(16) float smemf[4 * 1056];   // 4 waves x 32x33 f32
    const int t = threadIdx.x, lane = t & 63, w = t >> 6;

    if (blockIdx.x >= 128) {
        // ---------------- prep: cast 16 rows per block ----------------
        const int pb = blockIdx.x - 128;           // 0..255
        if (pb == 0) {
            if (t < 2) tail[t] = 0.f;              // zero loss accumulators
            if (t < 4) cnt[t] = 0;                 // zero proxy counters
        }
#pragma unroll
        for (int i = 0; i < 4; ++i) {
            const int r = pb * 16 + w * 4 + i;     // 0..4095
            const float* src = (r < NP) ? (Wm + (size_t)r * ND)
                                        : (prox + (size_t)(r - NP) * ND);
            float4 v0 = *(const float4*)(src + lane * 8);
            float4 v1 = *(const float4*)(src + lane * 8 + 4);
            if (r < NP) {
                *(ush8*)(WPb + (size_t)r * ND + lane * 8) = pack8(v0, v1);
            } else {
                float s = v0.x*v0.x + v0.y*v0.y + v0.z*v0.z + v0.w*v0.w
                        + v1.x*v1.x + v1.y*v1.y + v1.z*v1.z + v1.w*v1.w;
#pragma unroll
                for (int off = 32; off; off >>= 1) s += __shfl_down(s, off);
                if (lane == 0) pn2[r - NP] = s;
                // store 2*prox: bf16(2v) == 2*bf16(v) exactly (exponent shift)
                float4 d0 = make_float4(v0.x + v0.x, v0.y + v0.y,
                                        v0.z + v0.z, v0.w + v0.w);
                float4 d1 = make_float4(v1.x + v1.x, v1.y + v1.y,
                                        v1.z + v1.z, v1.w + v1.w);
                *(ush8*)(WPb + (size_t)r * ND + lane * 8) = pack8(d0, d1);
            }
        }
        return;
    }

    // -------- feat: one 32x32 tile, wave w owns K in [w*256, w*256+256) ------
    const int m0 = (blockIdx.x >> 4) * 32, n0 = (blockIdx.x & 15) * 32;
    const int fr = lane & 15, ck = (lane >> 4) * 8;
    const float* pA0 = x  + (size_t)(m0 + fr) * KIN + w * 256 + ck;
    const float* pA1 = pA0 + 16 * KIN;
    const float* pB0 = Wb + (size_t)(n0 + fr) * KIN + w * 256 + ck;
    const float* pB1 = pB0 + 16 * KIN;
    f32x4 acc[2][2] = {};
#pragma unroll
    for (int ks = 0; ks < 8; ++ks) {
        const int off = ks * 32;
        bf16x8 af0 = ldf8(pA0 + off);
        bf16x8 af1 = ldf8(pA1 + off);
        bf16x8 bf0 = ldf8(pB0 + off);
        bf16x8 bf1 = ldf8(pB1 + off);
        acc[0][0] = __builtin_amdgcn_mfma_f32_16x16x32_bf16(af0, bf0, acc[0][0], 0, 0, 0);
        acc[0][1] = __builtin_amdgcn_mfma_f32_16x16x32_bf16(af0, bf1, acc[0][1], 0, 0, 0);
        acc[1][0] = __builtin_amdgcn_mfma_f32_16x16x32_bf16(af1, bf0, acc[1][0], 0, 0, 0);
        acc[1][1] = __builtin_amdgcn_mfma_f32_16x16x32_bf16(af1, bf1, acc[1][1], 0, 0, 0);
    }
    // 4-way split-K reduce through LDS
    float* red = smemf + w * 1056;
    const int q = lane >> 4;
#pragma unroll
    for (int i = 0; i < 2; ++i)
#pragma unroll
        for (int j = 0; j < 2; ++j)
#pragma unroll
            for (int r = 0; r < 4; ++r)
                red[(16 * i + q * 4 + r) * 33 + 16 * j + fr] = acc[i][j][r];
    __syncthreads();
#pragma unroll
    for (int e = t; e < 1024; e += 256) {
        const int row = e >> 5, col = e & 31;
        const int idx = row * 33 + col;
        float v = smemf[idx] + smemf[idx + 1056]
                + smemf[idx + 2112] + smemf[idx + 3168];
        const int n = n0 + col;
        const float val = v + bb[n];
        feat32[(m0 + row) * ND + n] = val;
        featb [(m0 + row) * ND + n] = f2bf(val);
    }
}

__device__ __forceinline__ float block_reduce_sum(float v, float* sred)
{
    const int lane = threadIdx.x & 63, wave = threadIdx.x >> 6;
#pragma unroll
    for (int off = 32; off; off >>= 1) v += __shfl_down(v, off);
    if (lane == 0) sred[wave] = v;
    __syncthreads();
    float r = 0.f;
    if (threadIdx.x == 0) {
        r = sred[0] + sred[1] + sred[2] + sred[3];
    }
    __syncthreads();
    return r;   // valid on thread 0 only
}

// ---------------------------------------------------------------------------
// K2: head GEMM (round-0 proven 64x64 LDS-dbuf) + FUSED LOSS EPILOGUE.
// grid (64, 4): blockIdx.x = n-tile (0..31 -> out, 32..63 -> logits),
//               blockIdx.y = m-group (64 rows).
// Proxy blocks additionally compute per-row (max, sumexp) partials of their
// 64x64 logit tile; the 32nd finisher per m-group merges the partials
// (2-level LSE), gathers the target logit, computes feat row norms, and
// atomically folds loss/reg into tail. No spinning: "last block works".
// ---------------------------------------------------------------------------
__global__ __launch_bounds__(256) void k2_head(
    const unsigned short* __restrict__ featb,
    const unsigned short* __restrict__ WPb,
    const float* __restrict__ bm, const float* __restrict__ pn2,
    const float* __restrict__ feat32, const int* __restrict__ y,
    float* __restrict__ out, float* __restrict__ logits,
    float* __restrict__ pmx, float* __restrict__ psum,
    int* __restrict__ cnt, float* __restrict__ tail)
{
    // union: staging (16384 B) / logit tile 64 x stride-66 f32 (16896 B)
    __shared__ __align__(16) char smem[16896];
    __shared__ float sred[4];
    __shared__ int slast;
    unsigned short (*As)[64 * 32] = (unsigned short (*)[64 * 32])smem;
    unsigned short (*Bs)[64 * 32] = (unsigned short (*)[64 * 32])(smem + 8192);
    float* tile = (float*)smem;                      // stride 66

    const int t = threadIdx.x, lane = t & 63, w = t >> 6;
    const int n0 = blockIdx.x * 64;   // 64 n-tiles over 4096
    const int m0 = blockIdx.y * 64;   // 4 m-groups over 256
    const int srow = t >> 2, sc = (t & 3) * 8;
    const unsigned short* gA = featb + (size_t)(m0 + srow) * ND + sc;
    const unsigned short* gB = WPb   + (size_t)(n0 + srow) * ND + sc;
    ush8 va = *(const ush8*)gA;
    ush8 vb = *(const ush8*)gB;
    f32x4 acc[2][2] = {};
    const int wm = (w >> 1) * 32, wn = (w & 1) * 32;
    const int fr = lane & 15, fcol = (lane >> 4) * 8;

    for (int ks = 0; ks < ND / 32; ++ks) {
        *(ush8*)&As[ks & 1][srow * 32 + sc] = va;
        *(ush8*)&Bs[ks & 1][srow * 32 + sc] = vb;
        __syncthreads();
        if (ks + 1 < ND / 32) {
            va = *(const ush8*)(gA + (ks + 1) * 32);
            vb = *(const ush8*)(gB + (ks + 1) * 32);
        }
        const unsigned short* as = &As[ks & 1][0];
        const unsigned short* bs = &Bs[ks & 1][0];
        bf16x8 af0 = *(const bf16x8*)&as[(wm      + fr) * 32 + fcol];
        bf16x8 af1 = *(const bf16x8*)&as[(wm + 16 + fr) * 32 + fcol];
        bf16x8 bf0 = *(const bf16x8*)&bs[(wn      + fr) * 32 + fcol];
        bf16x8 bf1 = *(const bf16x8*)&bs[(wn + 16 + fr) * 32 + fcol];
        acc[0][0] = __builtin_amdgcn_mfma_f32_16x16x32_bf16(af0, bf0, acc[0][0], 0, 0, 0);
        acc[0][1] = __builtin_amdgcn_mfma_f32_16x16x32_bf16(af0, bf1, acc[0][1], 0, 0, 0);
        acc[1][0] = __builtin_amdgcn_mfma_f32_16x16x32_bf16(af1, bf0, acc[1][0], 0, 0, 0);
        acc[1][1] = __builtin_amdgcn_mfma_f32_16x16x32_bf16(af1, bf1, acc[1][1], 0, 0, 0);
    }

    const bool isProxy = (n0 >= NP);
    const int q = lane >> 4;

    if (!isProxy) {
        // plain classification-head epilogue
#pragma unroll
        for (int i = 0; i < 2; ++i)
#pragma unroll
            for (int j = 0; j < 2; ++j) {
                const int n = n0 + wn + 16 * j + fr;
                const float cadd = bm[n];
#pragma unroll
                for (int r = 0; r < 4; ++r) {
                    const int m = m0 + wm + 16 * i + q * 4 + r;
                    out[m * NP + n] = acc[i][j][r] + cadd;
                }
            }
        return;
    }

    // ---------------- proxy epilogue: store + LDS tile ----------------
    __syncthreads();                         // staging reads all done
#pragma unroll
    for (int i = 0; i < 2; ++i)
#pragma unroll
        for (int j = 0; j < 2; ++j) {
            const int ln = wn + 16 * j + fr;
            const int n  = n0 + ln;
            const float cadd = pn2[n - NP];
#pragma unroll
            for (int r = 0; r < 4; ++r) {
                const int lm = wm + 16 * i + q * 4 + r;
                const float v = acc[i][j][r] - cadd;
                logits[(m0 + lm) * NP + (n - NP)] = v;
                tile[lm * 66 + ln] = v;
            }
        }
    __syncthreads();

    // per-row partials over this tile's 64 cols: 4 lanes per row
    {
        const int row = t >> 2, g = t & 3;
        const float* tr = tile + row * 66 + g * 16;
        float mx = -INFINITY;
        float vv[16];
#pragma unroll
        for (int k = 0; k < 16; ++k) { vv[k] = tr[k]; mx = fmaxf(mx, vv[k]); }
        float m1 = fmaxf(mx, __shfl_xor(mx, 1));
        float MT = fmaxf(m1, __shfl_xor(m1, 2));
        float s = 0.f;
#pragma unroll
        for (int k = 0; k < 16; ++k) s += __expf(vv[k] - MT);
        s += __shfl_xor(s, 1);
        s += __shfl_xor(s, 2);
        if (g == 0) {
            const int pt = blockIdx.x - 32;          // 0..31
            pmx [pt * 256 + m0 + row] = MT;
            psum[pt * 256 + m0 + row] = s;
        }
    }
    __syncthreads();
    if (t == 0) {
        __threadfence();                             // publish logits+partials
        const int old = atomicAdd(&cnt[blockIdx.y], 1);
        slast = (old == 31);
    }
    __syncthreads();
    if (!slast) return;

    // ---------------- last proxy block of this m-group: the loss tail --------
    __threadfence();                                 // acquire others' writes
    const int row = t >> 2, g = t & 3, grow = m0 + row;

    // 2-level LSE merge over 32 tile partials
    float mx = -INFINITY;
#pragma unroll
    for (int p = g * 8; p < g * 8 + 8; ++p) mx = fmaxf(mx, pmx[p * 256 + grow]);
    float m1 = fmaxf(mx, __shfl_xor(mx, 1));
    float MX = fmaxf(m1, __shfl_xor(m1, 2));
    float s = 0.f;
#pragma unroll
    for (int p = g * 8; p < g * 8 + 8; ++p)
        s += psum[p * 256 + grow] * __expf(pmx[p * 256 + grow] - MX);
    s += __shfl_xor(s, 1);
    s += __shfl_xor(s, 2);

    // feat row norm: 4 lanes x 128 floats
    float n2 = 0.f;
    const float4* fp = (const float4*)(feat32 + (size_t)grow * ND + g * 128);
#pragma unroll
    for (int k = 0; k < 32; ++k) {
        float4 v = fp[k];
        n2 += v.x * v.x + v.y * v.y + v.z * v.z + v.w * v.w;
    }
    n2 += __shfl_xor(n2, 1);
    n2 += __shfl_xor(n2, 2);

    float lpv = 0.f, nmv = 0.f;
    if (g == 0) {
        const float ly = logits[(size_t)grow * NP + y[grow]];
        lpv = ly - MX - __logf(s);
        nmv = sqrtf(n2);
    }
    float S1 = block_reduce_sum(lpv, sred);
    __syncthreads();
    float S2 = block_reduce_sum(nmv, sred);
    if (t == 0) {
        atomicAdd(&tail[0], -S1 * (1.0f / (float)NB));
        atomicAdd(&tail[1],  S2 * (1.0f / (float)NB));
    }
}

extern "C" void kernel_launch(void* const* d_in, const int* in_sizes, int n_in,
                              void* d_out, int out_size, void* d_ws, size_t ws_size,
                              hipStream_t stream)
{
    const float* x       = (const float*)d_in[0];
    const int*   y       = (const int*)  d_in[1];
    const float* Wb      = (const float*)d_in[2];
    const float* bb      = (const float*)d_in[3];
    const float* Wm      = (const float*)d_in[4];
    const float* bm      = (const float*)d_in[5];
    const float* proxies = (const float*)d_in[6];

    char* ws = (char*)d_ws;
    unsigned short* WPb    = (unsigned short*)(ws + OFF_WPB);
    float*          feat32 = (float*)(ws + OFF_FEAT32);
    unsigned short* featb  = (unsigned short*)(ws + OFF_FEATB);
    float*          pn2    = (float*)(ws + OFF_PN2);
    float*          logits = (float*)(ws + OFF_LOGITS);
    float*          pmx    = (float*)(ws + OFF_PMX);
    float*          psum   = (float*)(ws + OFF_PSUM);
    int*            cnt    = (int*)  (ws + OFF_CNT);

    float* out  = (float*)d_out;
    float* tail = out + (size_t)NB * NP;

    k1_featprep<<<dim3(384), dim3(256), 0, stream>>>(
        x, Wb, bb, Wm, proxies, WPb, pn2, feat32, featb, tail, cnt);
    k2_head<<<dim3(NTOT / 64, NB / 64), dim3(256), 0, stream>>>(
        featb, WPb, bm, pn2, feat32, y, out, logits, pmx, psum, cnt, tail);
}